// Round 3
// baseline (593.312 us; speedup 1.0000x reference)
//
#include <hip/hip_runtime.h>
#include <stdint.h>

// SO2MLP: out = so2_linear(rot_act(so2_linear(x,W1)), W2)
// Restructured: Xr = rotate(x); A = leaky(Xr@W1^T); G = A@W2^T; out = rotate_back(G).
//
// R3: so2_gemm pipelined: 2(M)x4(N) wave grid (halves LDS af re-reads),
// T=4 M-tiles per block (amortizes 2x W duplication), A2B double-buffer with
// ONE barrier per hidden-chunk {GEMM2(c-1) || GEMM1(c)}, epilogue as direct
// 2B global stores (32B-sector-complete), 5 barriers/tile vs 11.

#define LMAX 6
#define NN 20000
#define RIN 256
#define RHID 512
#define ROUT 256
#define MTILE 64
#define NMT 626              // 40064/64
#define MPAD (NMT*MTILE)     // 40064
#define TILES 4
#define NBX ((NMT + TILES - 1) / TILES)   // 157

#define A2_STRIDE 272        // 64x272x2buf = 34816 B

typedef __attribute__((ext_vector_type(8))) short short8;
typedef __attribute__((ext_vector_type(4))) float f32x4;

__device__ __forceinline__ uint16_t f2bf(float f) {
  uint32_t x = __builtin_bit_cast(uint32_t, f);
  x += 0x7fffu + ((x >> 16) & 1u);   // round-to-nearest-even
  return (uint16_t)(x >> 16);
}
__device__ __forceinline__ float bf2f(uint16_t u) {
  return __builtin_bit_cast(float, ((uint32_t)u) << 16);
}

__device__ __forceinline__ f32x4 mfma16(short8 a, short8 b, f32x4 c) {
  return __builtin_amdgcn_mfma_f32_16x16x32_bf16(a, b, c, 0, 0, 0);
}

// ---------------------------------------------------------------------------
// K1a: weights fp32 -> bf16 in fragment-linear layout (verified R1/R2).
// B-fragment: lane holds col=lane&15, k = 8*(lane>>4)+j (j=0..7 contiguous);
// each (ofrag,kstep) fragment = 64 lanes x 16B = 1KB contiguous.
// ---------------------------------------------------------------------------
__global__ void prep_weights(const float* __restrict__ W1, const float* __restrict__ W2,
                             uint16_t* __restrict__ w1f, uint16_t* __restrict__ w2f) {
  int idx = blockIdx.x * 256 + threadIdx.x;
  if (idx >= LMAX * RHID * RIN) return;
  {
    // W1[l][o][i], K=RIN=256 -> 8 ksteps
    int l = idx / (RHID * RIN);
    int rem = idx - l * (RHID * RIN);
    int o = rem >> 8;
    int i = rem & 255;
    int lane = ((i >> 3) & 3) * 16 + (o & 15);
    size_t dst = (size_t)l * (RHID * RIN) +
                 ((((size_t)(o >> 4) * 8 + (i >> 5)) * 64 + lane) * 8 + (i & 7));
    w1f[dst] = f2bf(W1[idx]);
  }
  {
    // W2[l][o][j], K=RHID=512 -> 16 ksteps
    int l = idx / (ROUT * RHID);
    int rem = idx - l * (ROUT * RHID);
    int o = rem >> 9;
    int j = rem & 511;
    int lane = ((j >> 3) & 3) * 16 + (o & 15);
    size_t dst = (size_t)l * (ROUT * RHID) +
                 ((((size_t)(o >> 4) * 16 + (j >> 5)) * 64 + lane) * 8 + (j & 7));
    w2f[dst] = f2bf(W2[idx]);
  }
}

// ---------------------------------------------------------------------------
// K1b: input rotation + bf16 cast + degree-planar relayout.
// ---------------------------------------------------------------------------
__global__ void prep_x(const float* __restrict__ x, const float* __restrict__ rot,
                       uint16_t* __restrict__ xr) {
  int t = blockIdx.x * 256 + threadIdx.x;   // t = n*256 + i
  if (t >= NN * RIN) return;
  int n = t >> 8, i = t & 255;
  const float4* xp = (const float4*)(x + (size_t)t * 12);
  float4 v0 = xp[0], v1 = xp[1], v2 = xp[2];
  float xv[12] = {v0.x, v0.y, v0.z, v0.w, v1.x, v1.y, v1.z, v1.w, v2.x, v2.y, v2.z, v2.w};
  const float* rp = rot + (size_t)n * 24;   // rot[n][l][m][c]
#pragma unroll
  for (int l = 0; l < LMAX; ++l) {
    float c0 = xv[2 * l], c1 = xv[2 * l + 1];
    float r00 = rp[4 * l + 0], r01 = rp[4 * l + 1];
    float r10 = rp[4 * l + 2], r11 = rp[4 * l + 3];
    float a0 = c0 * r00 + c1 * r10;   // c=0
    float a1 = c0 * r01 + c1 * r11;   // c=1
    size_t base = (size_t)l * MPAD * RIN + (size_t)(2 * n) * RIN + i;
    xr[base] = f2bf(a0);
    xr[base + RIN] = f2bf(a1);
  }
}

// ---------------------------------------------------------------------------
// K2: pipelined fused dual GEMM. 512 thr = 8 waves = 2(M) x 4(N).
// Per tile (64 rows): 4 hidden chunks of 128. Chunk region:
//   { GEMM2(c-1) || GEMM1(c) } ; leaky->A2[c&1] ; bar        (1 bar/chunk)
// Tile boundary: { GEMM2(3) ; stage Xs(t+1) ; EPI(t) } ; bar ; {GEMM1(0)} bar
// ---------------------------------------------------------------------------
__global__ __launch_bounds__(512, 4) void so2_gemm(
    const uint16_t* __restrict__ xr,
    const uint16_t* __restrict__ w1f,
    const uint16_t* __restrict__ w2f,
    uint16_t* __restrict__ g) {
  __shared__ alignas(16) uint8_t Xs[MTILE * 512];           // 32768, XOR-swizzled
  __shared__ alignas(16) uint8_t A2[2][MTILE * A2_STRIDE];  // 2 x 17408

  const int l = blockIdx.y;
  const int tile0 = blockIdx.x * TILES;
  const int Tv = min(TILES, NMT - tile0);   // 4, or 2 for the last block
  const int tid = threadIdx.x;
  const int lane = tid & 63;
  const int wid = tid >> 6;
  const int wn = wid & 3;     // N-quarter (hidden / out cols)
  const int wm = wid >> 2;    // M-half (rows)
  const int l15 = lane & 15;
  const int l4 = lane >> 4;

  const uint16_t* w1p = w1f + (size_t)l * (RHID * RIN);
  const uint16_t* w2p = w2f + (size_t)l * (ROUT * RHID);
  const uint16_t* xrl = xr + (size_t)l * MPAD * RIN;
  uint16_t* gl = g + (size_t)l * MPAD * ROUT;

  f32x4 acc1[2][2];   // [mf][fc] GEMM1 chunk accum
  f32x4 acc2[2][4];   // [mf][nf] GEMM2 running accum (full K)
#pragma unroll
  for (int a = 0; a < 2; ++a)
#pragma unroll
    for (int b = 0; b < 4; ++b) acc2[a][b] = (f32x4){0.f, 0.f, 0.f, 0.f};

  auto STAGE = [&](int t) {   // stage tile (tile0+t): 64 rows x 512B, swizzled
    const char* xsrc = (const char*)(xrl + (size_t)(tile0 + t) * MTILE * RIN);
#pragma unroll
    for (int it = 0; it < 4; ++it) {
      int off = it * 8192 + tid * 16;
      int row = off >> 9;
      int colb = off & 511;
      short8 v = *(const short8*)(xsrc + off);
      *(short8*)(Xs + row * 512 + (colb ^ ((row & 7) << 4))) = v;
    }
  };

  auto G1 = [&](int oc) {   // acc1 = Xs(rows wm-half) @ W1[frags oc*8+wn*2,+1]
#pragma unroll
    for (int a = 0; a < 2; ++a)
#pragma unroll
      for (int b = 0; b < 2; ++b) acc1[a][b] = (f32x4){0.f, 0.f, 0.f, 0.f};
    const uint16_t* w1c0 = w1p + (size_t)(oc * 8 + wn * 2) * (8 * 64 * 8);
    const uint16_t* w1c1 = w1c0 + 8 * 64 * 8;
#pragma unroll
    for (int ks = 0; ks < 8; ++ks) {
      short8 b0 = *(const short8*)(w1c0 + ((size_t)ks * 64 + lane) * 8);
      short8 b1 = *(const short8*)(w1c1 + ((size_t)ks * 64 + lane) * 8);
#pragma unroll
      for (int mf = 0; mf < 2; ++mf) {
        int row = wm * 32 + mf * 16 + l15;
        int colb = ks * 64 + l4 * 16;
        short8 a = *(const short8*)(Xs + row * 512 + (colb ^ ((row & 7) << 4)));
        acc1[mf][0] = mfma16(a, b0, acc1[mf][0]);
        acc1[mf][1] = mfma16(a, b1, acc1[mf][1]);
      }
    }
  };

  auto WA2 = [&](int oc) {   // leaky(acc1) -> A2[oc&1]
    uint8_t* buf = A2[oc & 1];
#pragma unroll
    for (int mf = 0; mf < 2; ++mf)
#pragma unroll
      for (int fc = 0; fc < 2; ++fc)
#pragma unroll
        for (int r = 0; r < 4; ++r) {
          int row = wm * 32 + mf * 16 + l4 * 4 + r;   // D: row=(lane>>4)*4+reg
          int col = wn * 32 + fc * 16 + l15;          // D: col=lane&15
          float v = acc1[mf][fc][r];
          v = v >= 0.f ? v : 0.01f * v;
          *(uint16_t*)(buf + row * A2_STRIDE + col * 2) = f2bf(v);
        }
  };

  auto G2 = [&](int oc) {   // acc2 += A2[oc&1](rows wm-half) @ W2[frags wn*4..+4]
    const uint8_t* buf = A2[oc & 1];
#pragma unroll
    for (int ks2 = 0; ks2 < 4; ++ks2) {
      short8 a2[2];
#pragma unroll
      for (int mf = 0; mf < 2; ++mf)
        a2[mf] = *(const short8*)(buf + (wm * 32 + mf * 16 + l15) * A2_STRIDE +
                                  ks2 * 64 + l4 * 16);
#pragma unroll
      for (int nf = 0; nf < 4; ++nf) {
        short8 b = *(const short8*)(w2p + ((size_t)((wn * 4 + nf) * 16 + oc * 4 + ks2) * 64 + lane) * 8);
#pragma unroll
        for (int mf = 0; mf < 2; ++mf)
          acc2[mf][nf] = mfma16(a2[mf], b, acc2[mf][nf]);
      }
    }
  };

  auto EPI = [&](int t) {   // acc2 -> g (2B stores, 32B-sector-complete), reset
    uint16_t* gb = gl + (size_t)(tile0 + t) * MTILE * ROUT;
#pragma unroll
    for (int mf = 0; mf < 2; ++mf)
#pragma unroll
      for (int nf = 0; nf < 4; ++nf) {
#pragma unroll
        for (int r = 0; r < 4; ++r) {
          int row = wm * 32 + mf * 16 + l4 * 4 + r;
          int col = wn * 64 + nf * 16 + l15;
          gb[(size_t)row * ROUT + col] = f2bf(acc2[mf][nf][r]);
        }
        acc2[mf][nf] = (f32x4){0.f, 0.f, 0.f, 0.f};
      }
  };

  // ---- pipeline ----
  STAGE(0);
  __syncthreads();
  G1(0);
  WA2(0);
  __syncthreads();

  for (int c = 1; c < 4 * Tv; ++c) {
    int oc = c & 3;
    if (oc == 0) {
      int t = c >> 2;
      G2(3);          // finish previous tile's last chunk
      STAGE(t);       // Xs readers (G1(3)) were pre-barrier; safe
      EPI(t - 1);     // acc2 complete; direct global stores + reset
      __syncthreads();
      G1(0);
      WA2(0);
      __syncthreads();
    } else {
      G2(oc - 1);     // reads A2[(oc-1)&1], written pre-barrier
      G1(oc);         // independent: Xs + W1 -> MFMA, interleaves with G2
      WA2(oc);        // writes A2[oc&1]; its prior readers were 2 bars ago
      __syncthreads();
    }
  }
  G2(3);
  EPI(Tv - 1);
}

// ---------------------------------------------------------------------------
// K3: output rotation + fp32 store, fully coalesced (48 B per thread).
// ---------------------------------------------------------------------------
__global__ void post_out(const uint16_t* __restrict__ g, const float* __restrict__ rot,
                         float* __restrict__ out) {
  int n = blockIdx.x;
  int o = threadIdx.x;
  const float* rp = rot + (size_t)n * 24;
  float res[12];
#pragma unroll
  for (int l = 0; l < LMAX; ++l) {
    size_t base = (size_t)l * MPAD * ROUT + (size_t)(2 * n) * ROUT + o;
    float g0 = bf2f(g[base]);
    float g1 = bf2f(g[base + ROUT]);
    res[2 * l]     = rp[4 * l + 0] * g0 + rp[4 * l + 1] * g1;   // m=0
    res[2 * l + 1] = rp[4 * l + 2] * g0 + rp[4 * l + 3] * g1;   // m=1
  }
  float4* op = (float4*)(out + (size_t)(n * 256 + o) * 12);
  op[0] = make_float4(res[0], res[1], res[2], res[3]);
  op[1] = make_float4(res[4], res[5], res[6], res[7]);
  op[2] = make_float4(res[8], res[9], res[10], res[11]);
}

// ---------------------------------------------------------------------------
extern "C" void kernel_launch(void* const* d_in, const int* in_sizes, int n_in,
                              void* d_out, int out_size, void* d_ws, size_t ws_size,
                              hipStream_t stream) {
  (void)in_sizes; (void)n_in; (void)out_size;
  const float* x   = (const float*)d_in[0];
  const float* rot = (const float*)d_in[1];
  const float* W1  = (const float*)d_in[2];
  const float* W2  = (const float*)d_in[3];
  float* out = (float*)d_out;

  // Scratch plan:
  //   d_out (245.76 MB, overwritten by K3 at the end) doubles as scratch:
  //     [0, 123.08 MB)          Xr: 6 planes of [MPAD][RIN] bf16
  //     [123.08, 124.65 MB)     W1 bf16 fragment-linear
  //     [124.65, 126.22 MB)     W2 bf16 fragment-linear
  //   d_ws: G: 6 planes of [MPAD][ROUT] bf16 = 123,076,608 B
  const size_t xr_elems = (size_t)LMAX * MPAD * RIN;        // 61,538,304
  const size_t w_elems  = (size_t)LMAX * RHID * RIN;        // 786,432 (same for W2)
  if (ws_size < (size_t)LMAX * MPAD * ROUT * 2) return;     // need 123,076,608 B

  uint16_t* xr  = (uint16_t*)d_out;
  uint16_t* w1f = xr + xr_elems;
  uint16_t* w2f = w1f + w_elems;
  uint16_t* g   = (uint16_t*)d_ws;

  prep_weights<<<3072, 256, 0, stream>>>(W1, W2, w1f, w2f);
  prep_x<<<20000, 256, 0, stream>>>(x, rot, xr);
  dim3 gg(NBX, LMAX);
  so2_gemm<<<gg, 512, 0, stream>>>(xr, w1f, w2f, g);
  post_out<<<20000, 256, 0, stream>>>(g, rot, out);
}

// Round 4
// 541.066 us; speedup vs baseline: 1.0966x; 1.0966x over previous
//
#include <hip/hip_runtime.h>
#include <stdint.h>

// SO2MLP: out = so2_linear(rot_act(so2_linear(x,W1)), W2)
// Restructured: Xr = rotate(x); A = leaky(Xr@W1^T); G = A@W2^T; out = rotate_back(G).
//
// R4: so2_gemm rebuilt on 32x32x16 MFMA (2x FLOP per LDS byte vs 16x16x32).
// 2 hidden chunks of 256; G1 dup-free W1 (wave owns 1 hidden frag/chunk);
// G2 wm-split with 2 out-frags/wave (a2 reuse, W2 dup x2 into cheap L2).
// Full-granule XOR swizzle (g ^= row&31) -> all b128 LDS ops <=2-way.
// 5 barriers/tile. LDS 64KB (2 blocks/CU). Epilogue via LDS staging
// (R3 lesson: direct 2B global stores cause RMW catastrophe).

#define LMAX 6
#define NN 20000
#define RIN 256
#define RHID 512
#define ROUT 256
#define MTILE 64
#define NMT 626              // 40064/64
#define MPAD (NMT*MTILE)     // 40064

typedef __attribute__((ext_vector_type(8))) short short8;
typedef __attribute__((ext_vector_type(16))) float f32x16;

__device__ __forceinline__ uint16_t f2bf(float f) {
  uint32_t x = __builtin_bit_cast(uint32_t, f);
  x += 0x7fffu + ((x >> 16) & 1u);   // round-to-nearest-even
  return (uint16_t)(x >> 16);
}
__device__ __forceinline__ float bf2f(uint16_t u) {
  return __builtin_bit_cast(float, ((uint32_t)u) << 16);
}

__device__ __forceinline__ f32x16 mfma32(short8 a, short8 b, f32x16 c) {
  return __builtin_amdgcn_mfma_f32_32x32x16_bf16(a, b, c, 0, 0, 0);
}

// 512B-row LDS address with granule swizzle: bank set depends only on the
// 16B-granule index; XOR with row&31 makes 32-lane column reads conflict-free.
__device__ __forceinline__ int swz512(int row, int colb) {
  return row * 512 + ((((colb >> 4) ^ row) & 31) << 4) + (colb & 15);
}

// ---------------------------------------------------------------------------
// K1a: weights fp32 -> bf16 in 32x32x16 B-fragment-linear layout.
// B frag: col = lane&31, k = (lane>>5)*8 + e (e=0..7 contiguous);
// fragment (f,kstep) stored as 64 lanes x 16B = 1KB contiguous.
// ---------------------------------------------------------------------------
__global__ void prep_weights(const float* __restrict__ W1, const float* __restrict__ W2,
                             uint16_t* __restrict__ w1f, uint16_t* __restrict__ w2f) {
  int idx = blockIdx.x * 256 + threadIdx.x;
  if (idx >= LMAX * RHID * RIN) return;
  {
    // W1[l][o][i], K=RIN=256 -> 16 ksteps of 16; 16 out-frags of 32
    int l = idx / (RHID * RIN);
    int rem = idx - l * (RHID * RIN);
    int o = rem >> 8;
    int i = rem & 255;
    int lane = ((i >> 3) & 1) * 32 + (o & 31);
    size_t dst = (size_t)l * (RHID * RIN) +
                 ((((size_t)(o >> 5) * 16 + (i >> 4)) * 64 + lane) * 8 + (i & 7));
    w1f[dst] = f2bf(W1[idx]);
  }
  {
    // W2[l][o][j], K=RHID=512 -> 32 ksteps of 16; 8 out-frags of 32
    int l = idx / (ROUT * RHID);
    int rem = idx - l * (ROUT * RHID);
    int o = rem >> 9;
    int j = rem & 511;
    int lane = ((j >> 3) & 1) * 32 + (o & 31);
    size_t dst = (size_t)l * (ROUT * RHID) +
                 ((((size_t)(o >> 5) * 32 + (j >> 4)) * 64 + lane) * 8 + (j & 7));
    w2f[dst] = f2bf(W2[idx]);
  }
}

// ---------------------------------------------------------------------------
// K1b: input rotation + bf16 cast + degree-planar relayout.
// ---------------------------------------------------------------------------
__global__ void prep_x(const float* __restrict__ x, const float* __restrict__ rot,
                       uint16_t* __restrict__ xr) {
  int t = blockIdx.x * 256 + threadIdx.x;   // t = n*256 + i
  if (t >= NN * RIN) return;
  int n = t >> 8, i = t & 255;
  const float4* xp = (const float4*)(x + (size_t)t * 12);
  float4 v0 = xp[0], v1 = xp[1], v2 = xp[2];
  float xv[12] = {v0.x, v0.y, v0.z, v0.w, v1.x, v1.y, v1.z, v1.w, v2.x, v2.y, v2.z, v2.w};
  const float* rp = rot + (size_t)n * 24;   // rot[n][l][m][c]
#pragma unroll
  for (int l = 0; l < LMAX; ++l) {
    float c0 = xv[2 * l], c1 = xv[2 * l + 1];
    float r00 = rp[4 * l + 0], r01 = rp[4 * l + 1];
    float r10 = rp[4 * l + 2], r11 = rp[4 * l + 3];
    float a0 = c0 * r00 + c1 * r10;   // c=0
    float a1 = c0 * r01 + c1 * r11;   // c=1
    size_t base = (size_t)l * MPAD * RIN + (size_t)(2 * n) * RIN + i;
    xr[base] = f2bf(a0);
    xr[base + RIN] = f2bf(a1);
  }
}

// ---------------------------------------------------------------------------
// K2: fused dual GEMM per (degree, 64-row tile), 32x32x16 MFMA.
// 512 thr = 8 waves. G1: wave owns hidden frag oc*8+wid, both m-frags.
// G2: wave (wm=wid&1, wn4=wid>>1) owns m-frag wm, out-frags wn4*2..+2.
// A-frag (assumed, symmetric to verified 16x16): row=lane&31, k=(lane>>5)*8+e.
// C/D (verified m74/m101): col=lane&31, row=(r&3)+8*(r>>2)+4*(lane>>5).
// ---------------------------------------------------------------------------
__global__ __launch_bounds__(512, 4) void so2_gemm(
    const uint16_t* __restrict__ xr,
    const uint16_t* __restrict__ w1f,
    const uint16_t* __restrict__ w2f,
    uint16_t* __restrict__ g) {
  __shared__ alignas(16) uint8_t Xs[MTILE * 512];   // 32KB, swizzled
  __shared__ alignas(16) uint8_t A2[MTILE * 512];   // 32KB, swizzled (256 hid x 2B)

  const int l = blockIdx.y;
  const int m0 = blockIdx.x * MTILE;
  const int tid = threadIdx.x;
  const int lane = tid & 63;
  const int wid = tid >> 6;
  const int l31 = lane & 31;
  const int lh = lane >> 5;    // 0/1: selects k-octet
  const int wm = wid & 1;      // G2 m-frag
  const int wn4 = wid >> 1;    // G2 out quarter

  const uint16_t* w1p = w1f + (size_t)l * (RHID * RIN);
  const uint16_t* w2p = w2f + (size_t)l * (ROUT * RHID);

  // ---- stage Xr tile (64 rows x 512B) into swizzled LDS ----
  const char* xsrc = (const char*)(xr + (size_t)l * MPAD * RIN + (size_t)m0 * RIN);
#pragma unroll
  for (int it = 0; it < 4; ++it) {
    int off = it * 8192 + tid * 16;
    int row = off >> 9;
    int colb = off & 511;
    short8 v = *(const short8*)(xsrc + off);
    *(short8*)(Xs + swz512(row, colb)) = v;
  }
  __syncthreads();

  f32x16 acc1[2];   // [mf] G1 chunk accum (hidden frag oc*8+wid)
  f32x16 acc2[2];   // [nf] G2 running accum (m-frag wm, out frag wn4*2+nf)
#pragma unroll
  for (int a = 0; a < 2; ++a) acc2[a] = (f32x16)(0.f);

  auto G1 = [&](int oc) {
#pragma unroll
    for (int a = 0; a < 2; ++a) acc1[a] = (f32x16)(0.f);
    const uint16_t* wc = w1p + (size_t)(oc * 8 + wid) * (16 * 64 * 8);
#pragma unroll
    for (int ks = 0; ks < 16; ++ks) {
      short8 b = *(const short8*)(wc + ((size_t)ks * 64 + lane) * 8);
#pragma unroll
      for (int mf = 0; mf < 2; ++mf) {
        int row = mf * 32 + l31;
        short8 a = *(const short8*)(Xs + swz512(row, ks * 32 + lh * 16));
        acc1[mf] = mfma32(a, b, acc1[mf]);
      }
    }
  };

  auto WA2 = [&]() {   // leaky(acc1) -> A2 (chunk-local hidden cols wid*32..+32)
#pragma unroll
    for (int mf = 0; mf < 2; ++mf)
#pragma unroll
      for (int r = 0; r < 16; ++r) {
        int row = mf * 32 + (r & 3) + 8 * (r >> 2) + 4 * lh;
        int colb = (wid * 32 + l31) * 2;
        float v = acc1[mf][r];
        v = v >= 0.f ? v : 0.01f * v;
        *(uint16_t*)(A2 + swz512(row, colb)) = f2bf(v);
      }
  };

  auto G2 = [&](int oc) {   // acc2 += A2(m-frag wm) @ W2 frags wn4*2..+2
#pragma unroll
    for (int ks = 0; ks < 16; ++ks) {
      int row = wm * 32 + l31;
      short8 a = *(const short8*)(A2 + swz512(row, ks * 32 + lh * 16));
#pragma unroll
      for (int nf = 0; nf < 2; ++nf) {
        short8 b = *(const short8*)(w2p +
            ((size_t)((wn4 * 2 + nf) * 32 + oc * 16 + ks) * 64 + lane) * 8);
        acc2[nf] = mfma32(a, b, acc2[nf]);
      }
    }
  };

  G1(0);
  WA2();
  __syncthreads();
  G2(0);
  G1(1);
  __syncthreads();
  WA2();
  __syncthreads();
  G2(1);

  // ---- epilogue: acc2 -> bf16 via Xs (dead, reuse) -> coalesced 16B stores
#pragma unroll
  for (int nf = 0; nf < 2; ++nf)
#pragma unroll
    for (int r = 0; r < 16; ++r) {
      int row = wm * 32 + (r & 3) + 8 * (r >> 2) + 4 * lh;
      int colb = ((wn4 * 2 + nf) * 32 + l31) * 2;
      *(uint16_t*)(Xs + swz512(row, colb)) = f2bf(acc2[nf][r]);
    }
  __syncthreads();

  char* gdst = (char*)(g + (size_t)l * MPAD * ROUT + (size_t)m0 * ROUT);
#pragma unroll
  for (int it = 0; it < 4; ++it) {
    int off = it * 8192 + tid * 16;
    int row = off >> 9;
    int colb = off & 511;
    short8 v = *(const short8*)(Xs + swz512(row, colb));
    *(short8*)(gdst + off) = v;
  }
}

// ---------------------------------------------------------------------------
// K3: output rotation + fp32 store, fully coalesced (48 B per thread).
// ---------------------------------------------------------------------------
__global__ void post_out(const uint16_t* __restrict__ g, const float* __restrict__ rot,
                         float* __restrict__ out) {
  int n = blockIdx.x;
  int o = threadIdx.x;
  const float* rp = rot + (size_t)n * 24;
  float res[12];
#pragma unroll
  for (int l = 0; l < LMAX; ++l) {
    size_t base = (size_t)l * MPAD * ROUT + (size_t)(2 * n) * ROUT + o;
    float g0 = bf2f(g[base]);
    float g1 = bf2f(g[base + ROUT]);
    res[2 * l]     = rp[4 * l + 0] * g0 + rp[4 * l + 1] * g1;   // m=0
    res[2 * l + 1] = rp[4 * l + 2] * g0 + rp[4 * l + 3] * g1;   // m=1
  }
  float4* op = (float4*)(out + (size_t)(n * 256 + o) * 12);
  op[0] = make_float4(res[0], res[1], res[2], res[3]);
  op[1] = make_float4(res[4], res[5], res[6], res[7]);
  op[2] = make_float4(res[8], res[9], res[10], res[11]);
}

// ---------------------------------------------------------------------------
extern "C" void kernel_launch(void* const* d_in, const int* in_sizes, int n_in,
                              void* d_out, int out_size, void* d_ws, size_t ws_size,
                              hipStream_t stream) {
  (void)in_sizes; (void)n_in; (void)out_size;
  const float* x   = (const float*)d_in[0];
  const float* rot = (const float*)d_in[1];
  const float* W1  = (const float*)d_in[2];
  const float* W2  = (const float*)d_in[3];
  float* out = (float*)d_out;

  // Scratch plan:
  //   d_out (245.76 MB, overwritten by K3 at the end) doubles as scratch:
  //     [0, 123.08 MB)          Xr: 6 planes of [MPAD][RIN] bf16
  //     [123.08, 124.65 MB)     W1 bf16 fragment-linear
  //     [124.65, 126.22 MB)     W2 bf16 fragment-linear
  //   d_ws: G: 6 planes of [MPAD][ROUT] bf16 = 123,076,608 B
  const size_t xr_elems = (size_t)LMAX * MPAD * RIN;        // 61,538,304
  const size_t w_elems  = (size_t)LMAX * RHID * RIN;        // 786,432 (same for W2)
  if (ws_size < (size_t)LMAX * MPAD * ROUT * 2) return;     // need 123,076,608 B

  uint16_t* xr  = (uint16_t*)d_out;
  uint16_t* w1f = xr + xr_elems;
  uint16_t* w2f = w1f + w_elems;
  uint16_t* g   = (uint16_t*)d_ws;

  prep_weights<<<3072, 256, 0, stream>>>(W1, W2, w1f, w2f);
  prep_x<<<20000, 256, 0, stream>>>(x, rot, xr);
  dim3 gg(NMT, LMAX);
  so2_gemm<<<gg, 512, 0, stream>>>(xr, w1f, w2f, g);
  post_out<<<20000, 256, 0, stream>>>(g, rot, out);
}

// Round 5
// 349.813 us; speedup vs baseline: 1.6961x; 1.5467x over previous
//
#include <hip/hip_runtime.h>
#include <stdint.h>

// SO2MLP: out = so2_linear(rot_act(so2_linear(x,W1)), W2)
// Restructured: Xr = rotate(x); A = leaky(Xr@W1^T); G = A@W2^T; out = rotate_back(G).
//
// R5 = R4 (32x32x16 MFMA dual-GEMM, granule-swizzled LDS, 0 bank conflicts)
// + spill fix: #pragma unroll 4 on k-loops (R4's full unroll hoisted 16 W-loads
//   -> blew the 128-reg cap -> ~300MB scratch traffic, the R4 regression)
// + nontemporal hints on streamed Xr loads / G stores (protect W in L2).

#define LMAX 6
#define NN 20000
#define RIN 256
#define RHID 512
#define ROUT 256
#define MTILE 64
#define NMT 626              // 40064/64
#define MPAD (NMT*MTILE)     // 40064

typedef __attribute__((ext_vector_type(8))) short short8;
typedef __attribute__((ext_vector_type(16))) float f32x16;

__device__ __forceinline__ uint16_t f2bf(float f) {
  uint32_t x = __builtin_bit_cast(uint32_t, f);
  x += 0x7fffu + ((x >> 16) & 1u);   // round-to-nearest-even
  return (uint16_t)(x >> 16);
}
__device__ __forceinline__ float bf2f(uint16_t u) {
  return __builtin_bit_cast(float, ((uint32_t)u) << 16);
}

__device__ __forceinline__ f32x16 mfma32(short8 a, short8 b, f32x16 c) {
  return __builtin_amdgcn_mfma_f32_32x32x16_bf16(a, b, c, 0, 0, 0);
}

// 512B-row LDS address with granule swizzle: bank set depends only on the
// 16B-granule index; XOR with row&31 makes 32-lane column reads conflict-free.
__device__ __forceinline__ int swz512(int row, int colb) {
  return row * 512 + ((((colb >> 4) ^ row) & 31) << 4) + (colb & 15);
}

// ---------------------------------------------------------------------------
// K1a: weights fp32 -> bf16 in 32x32x16 B-fragment-linear layout.
// B frag: col = lane&31, k = (lane>>5)*8 + e (e=0..7 contiguous);
// fragment (f,kstep) stored as 64 lanes x 16B = 1KB contiguous.
// ---------------------------------------------------------------------------
__global__ void prep_weights(const float* __restrict__ W1, const float* __restrict__ W2,
                             uint16_t* __restrict__ w1f, uint16_t* __restrict__ w2f) {
  int idx = blockIdx.x * 256 + threadIdx.x;
  if (idx >= LMAX * RHID * RIN) return;
  {
    // W1[l][o][i], K=RIN=256 -> 16 ksteps of 16; 16 out-frags of 32
    int l = idx / (RHID * RIN);
    int rem = idx - l * (RHID * RIN);
    int o = rem >> 8;
    int i = rem & 255;
    int lane = ((i >> 3) & 1) * 32 + (o & 31);
    size_t dst = (size_t)l * (RHID * RIN) +
                 ((((size_t)(o >> 5) * 16 + (i >> 4)) * 64 + lane) * 8 + (i & 7));
    w1f[dst] = f2bf(W1[idx]);
  }
  {
    // W2[l][o][j], K=RHID=512 -> 32 ksteps of 16; 8 out-frags of 32
    int l = idx / (ROUT * RHID);
    int rem = idx - l * (ROUT * RHID);
    int o = rem >> 9;
    int j = rem & 511;
    int lane = ((j >> 3) & 1) * 32 + (o & 31);
    size_t dst = (size_t)l * (ROUT * RHID) +
                 ((((size_t)(o >> 5) * 32 + (j >> 4)) * 64 + lane) * 8 + (j & 7));
    w2f[dst] = f2bf(W2[idx]);
  }
}

// ---------------------------------------------------------------------------
// K1b: input rotation + bf16 cast + degree-planar relayout.
// ---------------------------------------------------------------------------
__global__ void prep_x(const float* __restrict__ x, const float* __restrict__ rot,
                       uint16_t* __restrict__ xr) {
  int t = blockIdx.x * 256 + threadIdx.x;   // t = n*256 + i
  if (t >= NN * RIN) return;
  int n = t >> 8, i = t & 255;
  const float4* xp = (const float4*)(x + (size_t)t * 12);
  float4 v0 = xp[0], v1 = xp[1], v2 = xp[2];
  float xv[12] = {v0.x, v0.y, v0.z, v0.w, v1.x, v1.y, v1.z, v1.w, v2.x, v2.y, v2.z, v2.w};
  const float* rp = rot + (size_t)n * 24;   // rot[n][l][m][c]
#pragma unroll
  for (int l = 0; l < LMAX; ++l) {
    float c0 = xv[2 * l], c1 = xv[2 * l + 1];
    float r00 = rp[4 * l + 0], r01 = rp[4 * l + 1];
    float r10 = rp[4 * l + 2], r11 = rp[4 * l + 3];
    float a0 = c0 * r00 + c1 * r10;   // c=0
    float a1 = c0 * r01 + c1 * r11;   // c=1
    size_t base = (size_t)l * MPAD * RIN + (size_t)(2 * n) * RIN + i;
    xr[base] = f2bf(a0);
    xr[base + RIN] = f2bf(a1);
  }
}

// ---------------------------------------------------------------------------
// K2: fused dual GEMM per (degree, 64-row tile), 32x32x16 MFMA.
// 512 thr = 8 waves. G1: wave owns hidden frag oc*8+wid, both m-frags.
// G2: wave (wm=wid&1, wn4=wid>>1) owns m-frag wm, out-frags wn4*2..+2.
// A-frag: row=lane&31, k=(lane>>5)*8+e (verified in R4 run).
// C/D: col=lane&31, row=(r&3)+8*(r>>2)+4*(lane>>5) (verified).
// ---------------------------------------------------------------------------
__global__ __launch_bounds__(512, 4) void so2_gemm(
    const uint16_t* __restrict__ xr,
    const uint16_t* __restrict__ w1f,
    const uint16_t* __restrict__ w2f,
    uint16_t* __restrict__ g) {
  __shared__ alignas(16) uint8_t Xs[MTILE * 512];   // 32KB, swizzled
  __shared__ alignas(16) uint8_t A2[MTILE * 512];   // 32KB, swizzled (256 hid x 2B)

  const int l = blockIdx.y;
  const int m0 = blockIdx.x * MTILE;
  const int tid = threadIdx.x;
  const int lane = tid & 63;
  const int wid = tid >> 6;
  const int l31 = lane & 31;
  const int lh = lane >> 5;    // 0/1: selects k-octet
  const int wm = wid & 1;      // G2 m-frag
  const int wn4 = wid >> 1;    // G2 out quarter

  const uint16_t* w1p = w1f + (size_t)l * (RHID * RIN);
  const uint16_t* w2p = w2f + (size_t)l * (ROUT * RHID);

  // ---- stage Xr tile (64 rows x 512B) into swizzled LDS (nontemporal) ----
  const char* xsrc = (const char*)(xr + (size_t)l * MPAD * RIN + (size_t)m0 * RIN);
#pragma unroll
  for (int it = 0; it < 4; ++it) {
    int off = it * 8192 + tid * 16;
    int row = off >> 9;
    int colb = off & 511;
    short8 v = __builtin_nontemporal_load((const short8*)(xsrc + off));
    *(short8*)(Xs + swz512(row, colb)) = v;
  }
  __syncthreads();

  f32x16 acc1[2];   // [mf] G1 chunk accum (hidden frag oc*8+wid)
  f32x16 acc2[2];   // [nf] G2 running accum (m-frag wm, out frag wn4*2+nf)
#pragma unroll
  for (int a = 0; a < 2; ++a) acc2[a] = (f32x16)(0.f);

  auto G1 = [&](int oc) {
#pragma unroll
    for (int a = 0; a < 2; ++a) acc1[a] = (f32x16)(0.f);
    const uint16_t* wc = w1p + (size_t)(oc * 8 + wid) * (16 * 64 * 8);
#pragma unroll 4
    for (int ks = 0; ks < 16; ++ks) {
      short8 b = *(const short8*)(wc + ((size_t)ks * 64 + lane) * 8);
#pragma unroll
      for (int mf = 0; mf < 2; ++mf) {
        int row = mf * 32 + l31;
        short8 a = *(const short8*)(Xs + swz512(row, ks * 32 + lh * 16));
        acc1[mf] = mfma32(a, b, acc1[mf]);
      }
    }
  };

  auto WA2 = [&]() {   // leaky(acc1) -> A2 (chunk-local hidden cols wid*32..+32)
#pragma unroll
    for (int mf = 0; mf < 2; ++mf)
#pragma unroll
      for (int r = 0; r < 16; ++r) {
        int row = mf * 32 + (r & 3) + 8 * (r >> 2) + 4 * lh;
        int colb = (wid * 32 + l31) * 2;
        float v = acc1[mf][r];
        v = v >= 0.f ? v : 0.01f * v;
        *(uint16_t*)(A2 + swz512(row, colb)) = f2bf(v);
      }
  };

  auto G2 = [&](int oc) {   // acc2 += A2(m-frag wm) @ W2 frags wn4*2..+2
#pragma unroll 4
    for (int ks = 0; ks < 16; ++ks) {
      int row = wm * 32 + l31;
      short8 a = *(const short8*)(A2 + swz512(row, ks * 32 + lh * 16));
#pragma unroll
      for (int nf = 0; nf < 2; ++nf) {
        short8 b = *(const short8*)(w2p +
            ((size_t)((wn4 * 2 + nf) * 32 + oc * 16 + ks) * 64 + lane) * 8);
        acc2[nf] = mfma32(a, b, acc2[nf]);
      }
    }
  };

  G1(0);
  WA2();
  __syncthreads();
  G2(0);
  G1(1);
  __syncthreads();
  WA2();
  __syncthreads();
  G2(1);

  // ---- epilogue: acc2 -> bf16 via Xs (dead, reuse) -> coalesced 16B stores
#pragma unroll
  for (int nf = 0; nf < 2; ++nf)
#pragma unroll
    for (int r = 0; r < 16; ++r) {
      int row = wm * 32 + (r & 3) + 8 * (r >> 2) + 4 * lh;
      int colb = ((wn4 * 2 + nf) * 32 + l31) * 2;
      *(uint16_t*)(Xs + swz512(row, colb)) = f2bf(acc2[nf][r]);
    }
  __syncthreads();

  char* gdst = (char*)(g + (size_t)l * MPAD * ROUT + (size_t)m0 * ROUT);
#pragma unroll
  for (int it = 0; it < 4; ++it) {
    int off = it * 8192 + tid * 16;
    int row = off >> 9;
    int colb = off & 511;
    short8 v = *(const short8*)(Xs + swz512(row, colb));
    __builtin_nontemporal_store(v, (short8*)(gdst + off));
  }
}

// ---------------------------------------------------------------------------
// K3: output rotation + fp32 store, fully coalesced (48 B per thread).
// ---------------------------------------------------------------------------
__global__ void post_out(const uint16_t* __restrict__ g, const float* __restrict__ rot,
                         float* __restrict__ out) {
  int n = blockIdx.x;
  int o = threadIdx.x;
  const float* rp = rot + (size_t)n * 24;
  float res[12];
#pragma unroll
  for (int l = 0; l < LMAX; ++l) {
    size_t base = (size_t)l * MPAD * ROUT + (size_t)(2 * n) * ROUT + o;
    float g0 = bf2f(g[base]);
    float g1 = bf2f(g[base + ROUT]);
    res[2 * l]     = rp[4 * l + 0] * g0 + rp[4 * l + 1] * g1;   // m=0
    res[2 * l + 1] = rp[4 * l + 2] * g0 + rp[4 * l + 3] * g1;   // m=1
  }
  float4* op = (float4*)(out + (size_t)(n * 256 + o) * 12);
  op[0] = make_float4(res[0], res[1], res[2], res[3]);
  op[1] = make_float4(res[4], res[5], res[6], res[7]);
  op[2] = make_float4(res[8], res[9], res[10], res[11]);
}

// ---------------------------------------------------------------------------
extern "C" void kernel_launch(void* const* d_in, const int* in_sizes, int n_in,
                              void* d_out, int out_size, void* d_ws, size_t ws_size,
                              hipStream_t stream) {
  (void)in_sizes; (void)n_in; (void)out_size;
  const float* x   = (const float*)d_in[0];
  const float* rot = (const float*)d_in[1];
  const float* W1  = (const float*)d_in[2];
  const float* W2  = (const float*)d_in[3];
  float* out = (float*)d_out;

  // Scratch plan:
  //   d_out (245.76 MB, overwritten by K3 at the end) doubles as scratch:
  //     [0, 123.08 MB)          Xr: 6 planes of [MPAD][RIN] bf16
  //     [123.08, 124.65 MB)     W1 bf16 fragment-linear
  //     [124.65, 126.22 MB)     W2 bf16 fragment-linear
  //   d_ws: G: 6 planes of [MPAD][ROUT] bf16 = 123,076,608 B
  const size_t xr_elems = (size_t)LMAX * MPAD * RIN;        // 61,538,304
  const size_t w_elems  = (size_t)LMAX * RHID * RIN;        // 786,432 (same for W2)
  if (ws_size < (size_t)LMAX * MPAD * ROUT * 2) return;     // need 123,076,608 B

  uint16_t* xr  = (uint16_t*)d_out;
  uint16_t* w1f = xr + xr_elems;
  uint16_t* w2f = w1f + w_elems;
  uint16_t* g   = (uint16_t*)d_ws;

  prep_weights<<<3072, 256, 0, stream>>>(W1, W2, w1f, w2f);
  prep_x<<<20000, 256, 0, stream>>>(x, rot, xr);
  dim3 gg(NMT, LMAX);
  so2_gemm<<<gg, 512, 0, stream>>>(xr, w1f, w2f, g);
  post_out<<<20000, 256, 0, stream>>>(g, rot, out);
}